// Round 1
// baseline (199.568 us; speedup 1.0000x reference)
//
#include <hip/hip_runtime.h>

// LGCN_REL_EMB: relational graph conv with identity relation embeddings.
// Pipeline:
//   cnt[r*N+v]  = #{t : rel[t]==r, fr[t]==v}
//   inv         = 1/cnt (0 where cnt==0)
//   h[v,:]      = relu(bias1 + sum_t inv[rel,fr] * w1[rel, to, :])   for fr[t]==v
//   out[v,c]    = bias2[c] + sum_t inv[rel,fr] * dot(h[to,:], w2[rel,:,c])  for fr[t]==v

__global__ void k_count(const int* __restrict__ fr, const int* __restrict__ rel,
                        int* __restrict__ cnt, int T, int N) {
    int t = blockIdx.x * blockDim.x + threadIdx.x;
    if (t < T) atomicAdd(&cnt[rel[t] * N + fr[t]], 1);
}

__global__ void k_inv(const int* __restrict__ cnt, float* __restrict__ inv, int n) {
    int i = blockIdx.x * blockDim.x + threadIdx.x;
    if (i < n) {
        int c = cnt[i];
        inv[i] = (c > 0) ? 1.0f / (float)c : 0.0f;
    }
}

// one thread per (triple, e): h[fr*E + e] += inv * w1[(rel*N + to)*E + e]
__global__ void k_spmm1(const int* __restrict__ fr, const int* __restrict__ to,
                        const int* __restrict__ rel, const float* __restrict__ w1,
                        const float* __restrict__ inv, float* __restrict__ h,
                        int T, int N, int E) {
    int idx = blockIdx.x * blockDim.x + threadIdx.x;
    int t = idx / E;
    int e = idx - t * E;
    if (t < T) {
        int r = rel[t], f = fr[t], o = to[t];
        float w = inv[r * N + f];
        float v = w * w1[((size_t)r * N + o) * E + e];
        atomicAdd(&h[(size_t)f * E + e], v);
    }
}

__global__ void k_relu(float* __restrict__ h, const float* __restrict__ b1, int n, int E) {
    int i = blockIdx.x * blockDim.x + threadIdx.x;
    if (i < n) h[i] = fmaxf(h[i] + b1[i % E], 0.0f);
}

__global__ void k_outinit(float* __restrict__ out, const float* __restrict__ b2, int n, int C) {
    int i = blockIdx.x * blockDim.x + threadIdx.x;
    if (i < n) out[i] = b2[i % C];
}

// one thread per (triple, c): out[fr*C + c] += inv * sum_e h[to*E+e] * w2[(rel*E+e)*C + c]
__global__ void k_spmm2(const int* __restrict__ fr, const int* __restrict__ to,
                        const int* __restrict__ rel, const float* __restrict__ h,
                        const float* __restrict__ w2, const float* __restrict__ inv,
                        float* __restrict__ out, int T, int N, int E, int C) {
    int idx = blockIdx.x * blockDim.x + threadIdx.x;
    int t = idx / C;
    int c = idx - t * C;
    if (t < T) {
        int r = rel[t], f = fr[t], o = to[t];
        float w = inv[r * N + f];
        const float* __restrict__ hrow = h + (size_t)o * E;
        const float* __restrict__ w2c  = w2 + (size_t)r * E * C + c;
        float acc = 0.0f;
        #pragma unroll 8
        for (int e = 0; e < E; ++e) {
            acc += hrow[e] * w2c[(size_t)e * C];
        }
        atomicAdd(&out[(size_t)f * C + c], w * acc);
    }
}

extern "C" void kernel_launch(void* const* d_in, const int* in_sizes, int n_in,
                              void* d_out, int out_size, void* d_ws, size_t ws_size,
                              hipStream_t stream) {
    const int*   fr  = (const int*)d_in[0];
    const int*   to  = (const int*)d_in[1];
    const int*   rel = (const int*)d_in[2];
    const float* w1  = (const float*)d_in[3];
    const float* w2  = (const float*)d_in[4];
    const float* b1  = (const float*)d_in[5];
    const float* b2  = (const float*)d_in[6];
    float* out = (float*)d_out;

    const int T = in_sizes[0];
    const int E = in_sizes[5];
    const int C = in_sizes[6];
    const int R = in_sizes[4] / (E * C);
    const int N = in_sizes[3] / (R * E);

    // workspace layout: cnt (R*N int) | inv (R*N float) | h (N*E float)
    const size_t cnt_bytes = (size_t)R * N * sizeof(int);
    int*   cnt = (int*)d_ws;
    float* inv = (float*)((char*)d_ws + cnt_bytes);
    float* h   = (float*)((char*)d_ws + 2 * cnt_bytes);

    hipMemsetAsync(cnt, 0, cnt_bytes, stream);
    hipMemsetAsync(h, 0, (size_t)N * E * sizeof(float), stream);

    const int B = 256;
    k_count<<<(T + B - 1) / B, B, 0, stream>>>(fr, rel, cnt, T, N);
    k_inv<<<(R * N + B - 1) / B, B, 0, stream>>>(cnt, inv, R * N);

    long long n1 = (long long)T * E;
    k_spmm1<<<(int)((n1 + B - 1) / B), B, 0, stream>>>(fr, to, rel, w1, inv, h, T, N, E);

    k_relu<<<(N * E + B - 1) / B, B, 0, stream>>>(h, b1, N * E, E);
    k_outinit<<<(out_size + B - 1) / B, B, 0, stream>>>(out, b2, out_size, C);

    long long n2 = (long long)T * C;
    k_spmm2<<<(int)((n2 + B - 1) / B), B, 0, stream>>>(fr, to, rel, h, w2, inv, out, T, N, E, C);
}